// Round 6
// baseline (134.044 us; speedup 1.0000x reference)
//
#include <hip/hip_runtime.h>
#include <math.h>

// Problem constants
#define BATCH 64
#define SEQL  512
#define DIN   256
#define NF    256
#define KS    3
#define KF    (KS * NF)        // 768

// Fully fused combined-channel formulation (see prior rounds).
// This round:
//  * conv: ks-split wave pairing — 4 tiles of 64x128, wave pairs split the
//    4 k-slices (kh = wave&1 -> ks in {2kh, 2kh+1}): 12 LDS reads / 16 MFMA
//    per wave-region (was 16/16). Pairwise partial-sum reduction through
//    LDS at the end (panels dead), balanced j-pair exchange.
//  * phase G: operand swap (A=UT frag, B=x frag; same LDS reads) so D is
//    [e][xrow] -> lane holds 4 consecutive e -> Y epilogue uses b64 writes
//    instead of scalar b16 scatters.
#define XCH 512
#define KC  (KS * XCH)          // 1536
#define PROWS 130               // 128 out rows + 2 halo
#define PLD   128               // panel row stride (shorts) = 256 B
#define PSZ   (PROWS * PLD)     // 16640 shorts per panel

typedef __attribute__((ext_vector_type(8))) short short8;
typedef __attribute__((ext_vector_type(4))) float floatx4;
typedef __attribute__((ext_vector_type(16))) float floatx16;
typedef __attribute__((ext_vector_type(8))) unsigned short ushort8v;
typedef __attribute__((ext_vector_type(4))) unsigned short ushort4v;

static __device__ __forceinline__ unsigned short f2bf(float f) {
    unsigned int u = __float_as_uint(f);
    return (unsigned short)((u + 0x7FFF + ((u >> 16) & 1)) >> 16);  // RTNE
}

// async 16B/lane global->LDS; LDS dst = wave-uniform base + lane*16
static __device__ __forceinline__ void gl_lds16(const void* g, void* l) {
    __builtin_amdgcn_global_load_lds(
        (const __attribute__((address_space(1))) unsigned int*)g,
        (__attribute__((address_space(3))) unsigned int*)l, 16, 0, 0);
}

// ---------------------------------------------------------------------------
// pack: WcT[f][c] transpose (96 blk), UT[e][d] transpose (16 blk).
// 112 blocks x 256 threads.
// ---------------------------------------------------------------------------
__global__ __launch_bounds__(256) void pack_kernel(
    const float* __restrict__ U, const float* __restrict__ V,
    const float* __restrict__ Bw,
    unsigned short* __restrict__ WcT, unsigned short* __restrict__ UT)
{
    const int blk = blockIdx.x;
    const int t   = threadIdx.x;
    __shared__ unsigned short tile[64][64 + 2];

    if (blk < 96) {
        const int f0 = (blk & 3) * 64, c0 = (blk >> 2) * 64;
        const int fl = t & 63, cb = t >> 6;
        #pragma unroll
        for (int it = 0; it < 16; ++it) {
            const int cl = cb + it * 4;
            const int c  = c0 + cl;
            const int k  = c >> 9, ch = c & (XCH - 1);
            const float v = (ch < DIN) ? Bw[(size_t)ch * KF + k * NF + f0 + fl]
                                       : V[(size_t)(ch - DIN) * KF + k * NF + f0 + fl];
            tile[cl][fl] = f2bf(v);
        }
        __syncthreads();
        const int cl2 = t & 63, fb = t >> 6;
        #pragma unroll
        for (int it = 0; it < 16; ++it) {
            const int fl2 = fb + it * 4;
            WcT[(size_t)(f0 + fl2) * KC + c0 + cl2] = tile[cl2][fl2];
        }
    } else {
        const int bb = blk - 96;
        const int e0 = (bb & 3) * 64, d0 = (bb >> 2) * 64;
        const int el = t & 63, db = t >> 6;
        #pragma unroll
        for (int it = 0; it < 16; ++it) {
            const int dl = db + it * 4;
            tile[dl][el] = f2bf(U[(size_t)(d0 + dl) * DIN + e0 + el]);
        }
        __syncthreads();
        const int dl2 = t & 63, eb = t >> 6;
        #pragma unroll
        for (int it = 0; it < 16; ++it) {
            const int el2 = eb + it * 4;
            UT[(size_t)(e0 + el2) * DIN + d0 + dl2] = tile[dl2][el2];
        }
    }
}

// ---------------------------------------------------------------------------
// fused kernel. Grid 256 x 512. LDS 133.1 KB -> 1 block/CU (8 waves).
// ---------------------------------------------------------------------------
__global__ __launch_bounds__(512, 2) void fused_kernel(
    const float* __restrict__ x, const float* __restrict__ z,
    const unsigned short* __restrict__ UT,
    const unsigned short* __restrict__ WcT,
    const float* __restrict__ bias, float* __restrict__ out)
{
    __shared__ __align__(16) unsigned short lds[4 * PSZ];   // 133120 B

    const int tid  = threadIdx.x;
    const int lane = tid & 63;
    const int wave = tid >> 6;
    const int quad = lane >> 4, l16 = lane & 15;
    const int l32  = lane & 31, hi  = lane >> 5;
    const int r8   = lane >> 3, ud8 = lane & 7;

    const int bid   = blockIdx.x;
    const int b     = bid >> 2;
    const int lbase = (bid & 3) * 128;

    // conv wave-pairing: 4 tiles of 64 rows x 128 f, wave pair splits ks
    const int tile4 = wave >> 1;           // 0..3
    const int wr2   = tile4 >> 1;          // 0..1 : 64-row group
    const int wc2   = tile4 & 1;           // 0..1 : 128-f group
    const int kh    = wave & 1;            // K-half of the pair

    // conv accumulators: 2x4 of 32x32 tiles = 128 VGPR (partial K-sums)
    floatx16 acc2[2][4] = {};

    // B-staging buffer for conv region r (24 regions: r = (g*3+k)*2+hh):
    //   r<12 (g=0,1): dbuf in P2/P3 space; r>=12 (g=2,3): dbuf in P0/P1 space
    auto convBuf = [&](int r) -> unsigned short* {
        return (r < 12) ? (lds + 2 * PSZ + ((r & 1) ? 16384 : 0))
                        : (lds + ((r & 1) ? PSZ : 0));
    };
    // stage WcT block [256 f][64 ch] for region r (4 gl_lds16/wave)
    auto stageB = [&](int r) {
        unsigned short* buf = convBuf(r);
        const int g = r / 6, k = (r / 2) % 3, hh = r & 1;
        const unsigned short* gW = WcT + (size_t)k * XCH + g * 128 + hh * 64;
        #pragma unroll
        for (int c = 0; c < 4; ++c) {
            const int rr = wave * 32 + c * 8 + r8;
            gl_lds16(gW + (size_t)rr * KC + ((ud8 ^ (rr & 7)) << 3),
                     buf + (size_t)(wave * 32 + c * 8) * 64);
        }
    };
    // conv compute for region r: this wave does its 2 of the 4 ks-slices
    // for a 64x128 tile: per ks 2 af + 4 bf reads -> 8 MFMA.
    auto convRegion = [&](int r) {
        const unsigned short* buf = convBuf(r);
        const int g = r / 6, k = (r / 2) % 3, hh = r & 1;
        const unsigned short* P = lds + (size_t)g * PSZ;
        __builtin_amdgcn_s_setprio(1);
        #pragma unroll
        for (int ks2 = 0; ks2 < 2; ++ks2) {
            const int ks = kh * 2 + ks2;
            short8 af[2], bf[4];
            const int uwa = hh * 8 + ks * 2 + hi;
            #pragma unroll
            for (int i = 0; i < 2; ++i) {
                const int m = wr2 * 64 + i * 32 + l32 + k;
                af[i] = *(const short8*)&P[m * PLD + ((uwa ^ (m & 15)) << 3)];
            }
            const int uwb = ks * 2 + hi;
            #pragma unroll
            for (int j = 0; j < 4; ++j) {
                const int n = wc2 * 128 + j * 32 + l32;
                bf[j] = *(const short8*)&buf[n * 64 + ((uwb ^ (n & 7)) << 3)];
            }
            #pragma unroll
            for (int i = 0; i < 2; ++i)
                #pragma unroll
                for (int j = 0; j < 4; ++j)
                    acc2[i][j] = __builtin_amdgcn_mfma_f32_32x32x16_bf16(
                        af[i], bf[j], acc2[i][j], 0, 0, 0);
        }
        __builtin_amdgcn_s_setprio(0);
    };

    // ---------------- phase X: x -> P0, P1 (bf16, swizzled) ----------------
    #pragma unroll
    for (int p = 0; p < 2; ++p) {
        unsigned short* P = lds + (size_t)p * PSZ;
        #pragma unroll
        for (int it = 0; it < 5; ++it) {
            const int idx = tid + it * 512;
            if (idx < PROWS * 16) {
                const int row = idx >> 4, u = idx & 15;
                const int l = lbase - 1 + row;
                ushort8v h = {};
                if (l >= 0 && l < SEQL) {
                    const float* xp = x + ((size_t)b * SEQL + l) * DIN + p * 128 + u * 8;
                    const float4 v0 = *(const float4*)xp;
                    const float4 v1 = *(const float4*)(xp + 4);
                    h[0] = f2bf(v0.x); h[1] = f2bf(v0.y);
                    h[2] = f2bf(v0.z); h[3] = f2bf(v0.w);
                    h[4] = f2bf(v1.x); h[5] = f2bf(v1.y);
                    h[6] = f2bf(v1.z); h[7] = f2bf(v1.w);
                }
                *(ushort8v*)&P[row * PLD + ((u ^ (row & 15)) << 3)] = h;
            }
        }
    }

    // ---------------- conv part A: g = 0,1 (x panels), regions 0..11 -------
    stageB(0);
    __syncthreads();                       // X writes visible + stage(0) landed
    #pragma unroll 1
    for (int r = 0; r < 12; ++r) {
        if (r < 11) stageB(r + 1);         // issue-early: hides under compute
        convRegion(r);
        __syncthreads();
    }

    // ---------------- phase G: Y = (x@U)*sigmoid(z) -> P2, P3 --------------
    // Operand-swapped: accY = mfma(A=UT frag, B=x frag) so D = [e][xrow];
    // lane then holds 4 consecutive e per row -> b64 epilogue writes.
    // Single K-sweep (both e-halves); UT staged [256e][64d], dbuf in P2/P3.
    {
        floatx4 accY[2][9] = {};
        auto utBuf = [&](int kk) -> unsigned short* {
            return lds + 2 * PSZ + ((kk & 1) ? 16384 : 0);
        };
        auto stageU = [&](int kk) {
            unsigned short* buf = utBuf(kk);
            const unsigned short* gU = UT + (size_t)kk * 64;
            #pragma unroll
            for (int c = 0; c < 4; ++c) {
                const int rr = wave * 32 + c * 8 + r8;
                gl_lds16(gU + (size_t)rr * DIN + ((ud8 ^ (rr & 7)) << 3),
                         buf + (size_t)(wave * 32 + c * 8) * 64);
            }
        };
        stageU(0);
        __syncthreads();
        #pragma unroll 1
        for (int kk = 0; kk < 4; ++kk) {
            if (kk < 3) stageU(kk + 1);
            const unsigned short* buf = utBuf(kk);
            const unsigned short* P = lds + (size_t)(kk >> 1) * PSZ;
            const int dh = kk & 1;
            __builtin_amdgcn_s_setprio(1);
            #pragma unroll
            for (int ks = 0; ks < 2; ++ks) {
                short8 uf[2];
                #pragma unroll
                for (int eh = 0; eh < 2; ++eh) {
                    const int n = eh * 128 + wave * 16 + l16;   // UT row (e)
                    uf[eh] = *(const short8*)
                        &buf[n * 64 + (((ks * 4 + quad) ^ (n & 7)) << 3)];
                }
                #pragma unroll
                for (int i = 0; i < 9; ++i) {
                    const int row = i * 16 + l16;   // x row; >=130 garbage, masked below
                    const short8 xf = *(const short8*)
                        &P[row * PLD + (((dh * 8 + ks * 4 + quad) ^ (row & 15)) << 3)];
                    #pragma unroll
                    for (int eh = 0; eh < 2; ++eh)
                        accY[eh][i] = __builtin_amdgcn_mfma_f32_16x16x32_bf16(
                            uf[eh], xf, accY[eh][i], 0, 0, 0);
                }
            }
            __builtin_amdgcn_s_setprio(0);
            __syncthreads();
        }
        // epilogue: D[e][xrow] -> lane holds e = eh*128 + wave*16 + quad*4 + reg
        // for xrow = i*16 + l16. 4 consecutive e -> one b64 write per (eh,i).
        #pragma unroll
        for (int eh = 0; eh < 2; ++eh) {
            unsigned short* PY = lds + (size_t)(2 + eh) * PSZ;
            const int c0 = wave * 16 + quad * 4;        // within-panel e col base
            float zf[4];
            #pragma unroll
            for (int r2 = 0; r2 < 4; ++r2)
                zf[r2] = 1.0f /
                    (1.0f + expf(-z[(size_t)b * DIN + eh * 128 + c0 + r2]));
            const int u = c0 >> 3;
            #pragma unroll
            for (int i = 0; i < 9; ++i) {
                const int xrow = i * 16 + l16;
                if (xrow < PROWS) {
                    ushort4v h;
                    #pragma unroll
                    for (int r2 = 0; r2 < 4; ++r2)
                        h[r2] = f2bf(accY[eh][i][r2] * zf[r2]);
                    *(ushort4v*)&PY[xrow * PLD + ((u ^ (xrow & 15)) << 3) + (c0 & 7)] = h;
                }
            }
        }
    }

    // ---------------- conv part B: g = 2,3 (Y panels), regions 12..23 ------
    stageB(12);
    __syncthreads();                       // drains Y-epilogue ds_writes too
    #pragma unroll 1
    for (int r = 12; r < 24; ++r) {
        if (r < 23) stageB(r + 1);
        convRegion(r);
        __syncthreads();
    }

    // ---------------- pairwise kh-reduction + bias/relu/store --------------
    // Each wave writes its partial for the j-pair it does NOT own, reads the
    // partner's partial for the pair it owns, adds, stores. All panels dead:
    // per tile 8192 floats (2 areas of 4096 by writer kh). 131072 B total.
    {
        float* fbuf = (float*)lds;
        float* wA = fbuf + (size_t)tile4 * 8192 + (size_t)kh * 4096;
        #pragma unroll
        for (int jp = 0; jp < 2; ++jp) {
            if (jp != kh) {                 // write the pair we don't own
                #pragma unroll
                for (int i = 0; i < 2; ++i)
                    #pragma unroll
                    for (int jj = 0; jj < 2; ++jj)
                        #pragma unroll
                        for (int q = 0; q < 4; ++q) {
                            floatx4 v;
                            #pragma unroll
                            for (int c2 = 0; c2 < 4; ++c2)
                                v[c2] = acc2[i][jp * 2 + jj][q * 4 + c2];
                            *(floatx4*)&wA[(size_t)(((i * 2 + jj) * 4 + q) * 256
                                                    + lane * 4)] = v;
                        }
            }
        }
        __syncthreads();
        const float* rA = fbuf + (size_t)tile4 * 8192 + (size_t)(1 - kh) * 4096;
        #pragma unroll
        for (int jp = 0; jp < 2; ++jp) {
            if (jp == kh) {                 // reduce + store the pair we own
                #pragma unroll
                for (int jj = 0; jj < 2; ++jj) {
                    const int f  = wc2 * 128 + (jp * 2 + jj) * 32 + l32;
                    const float bv = bias[f];
                    #pragma unroll
                    for (int i = 0; i < 2; ++i) {
                        #pragma unroll
                        for (int q = 0; q < 4; ++q) {
                            const floatx4 v = *(const floatx4*)
                                &rA[(size_t)(((i * 2 + jj) * 4 + q) * 256 + lane * 4)];
                            #pragma unroll
                            for (int c2 = 0; c2 < 4; ++c2) {
                                const int reg  = q * 4 + c2;
                                const int rowl = wr2 * 64 + i * 32 +
                                                 (reg & 3) + 8 * (reg >> 2) + 4 * hi;
                                const float val =
                                    acc2[i][jp * 2 + jj][reg] + v[c2] + bv;
                                out[((size_t)b * SEQL + lbase + rowl) * NF + f] =
                                    fmaxf(val, 0.0f);
                            }
                        }
                    }
                }
            }
        }
    }
}

extern "C" void kernel_launch(void* const* d_in, const int* in_sizes, int n_in,
                              void* d_out, int out_size, void* d_ws, size_t ws_size,
                              hipStream_t stream) {
    const float* x    = (const float*)d_in[0];
    const float* z    = (const float*)d_in[1];
    const float* U    = (const float*)d_in[2];
    const float* V    = (const float*)d_in[3];
    const float* Bw   = (const float*)d_in[4];
    const float* bias = (const float*)d_in[5];

    unsigned short* WcT = (unsigned short*)d_ws;          // 256*1536*2 B
    unsigned short* UT  = WcT + (size_t)NF * KC;          // 256*256*2 B
    float* out = (float*)d_out;

    pack_kernel<<<dim3(112), 256, 0, stream>>>(U, V, Bw, WcT, UT);
    fused_kernel<<<dim3(256), 512, 0, stream>>>(x, z, UT, WcT, bias, out);
}